// Round 2
// baseline (242.700 us; speedup 1.0000x reference)
//
#include <hip/hip_runtime.h>

typedef __bf16 bf16_t;
typedef bf16_t bf16x8 __attribute__((ext_vector_type(8)));
typedef unsigned short u16x8 __attribute__((ext_vector_type(8)));
typedef float f32x4 __attribute__((ext_vector_type(4)));

union BF8 { u16x8 u; bf16x8 b; };

__device__ __forceinline__ unsigned short f2bf(float f) {
  unsigned int u = __float_as_uint(f);
  unsigned int r = (u + 0x7FFFu + ((u >> 16) & 1u)) >> 16;
  return (unsigned short)r;
}
__device__ __forceinline__ float bf2f(unsigned short s) {
  return __uint_as_float(((unsigned int)s) << 16);
}

// ---------------- prep: all weights -> bf16 hi/lo planes ---------------------
// W1h/W1l: [256][800] (c=a*64+o major, k padded 784->800 with zeros)
// W2h/W2l: [4][64][64]  W2t[a][o][k] = W2[a][k][o]
// Wbh/Wbl: [4][320][64] native W layout (B-frag ready)
__global__ __launch_bounds__(256) void kprep(const float* __restrict__ W1,
                                             const float* __restrict__ W2,
                                             const float* __restrict__ W,
                                             unsigned short* __restrict__ W1h,
                                             unsigned short* __restrict__ W1l,
                                             unsigned short* __restrict__ W2h,
                                             unsigned short* __restrict__ W2l,
                                             unsigned short* __restrict__ Wbh,
                                             unsigned short* __restrict__ Wbl) {
  int idx = blockIdx.x * 256 + threadIdx.x;
  if (idx < 204800) {
    int c = idx / 800, k = idx - c * 800;
    int a = c >> 6, o = c & 63;
    float v = (k < 784) ? W1[(a * 784 + k) * 64 + o] : 0.f;
    unsigned short hi = f2bf(v);
    W1h[idx] = hi;
    W1l[idx] = f2bf(v - bf2f(hi));
  }
  if (idx < 16384) {
    int a = idx >> 12, o = (idx >> 6) & 63, k = idx & 63;
    float v = W2[(a * 64 + k) * 64 + o];
    unsigned short hi = f2bf(v);
    W2h[idx] = hi;
    W2l[idx] = f2bf(v - bf2f(hi));
  }
  if (idx < 81920) {
    float v = W[idx];
    unsigned short hi = f2bf(v);
    Wbh[idx] = hi;
    Wbl[idx] = f2bf(v - bf2f(hi));
  }
}

// ---------------- kA: h = relu(x@W1 + b1), split-bf16, -> packed u32 ---------
// BM=128, BN=256(full), 4 waves (each: 2 M-tiles x 16 N-tiles), K=800 in 25 steps
__global__ __launch_bounds__(256, 2) void kA(const float* __restrict__ x,
                                             const float* __restrict__ b1,
                                             const unsigned short* __restrict__ W1h,
                                             const unsigned short* __restrict__ W1l,
                                             unsigned int* __restrict__ H) {
  __shared__ unsigned short xsh[128 * 40];
  __shared__ unsigned short xsl[128 * 40];
  __shared__ unsigned short wsh[256 * 40];
  __shared__ unsigned short wsl[256 * 40];
  __shared__ float b1s[256];
  const int tid = threadIdx.x;
  const int w   = tid >> 6;
  const int l   = tid & 63;
  const int l15 = l & 15;
  const int lg4 = l >> 4;
  const int k8  = lg4 * 8;
  const int b0  = blockIdx.x * 128;

  b1s[tid] = b1[tid];

  const f32x4 fz = {0.f, 0.f, 0.f, 0.f};
  f32x4 acc[2][16];
#pragma unroll
  for (int m = 0; m < 2; ++m)
#pragma unroll
    for (int n = 0; n < 16; ++n) acc[m][n] = fz;

  const int srow = tid >> 1;
  const int scb  = (tid & 1) * 16;

  for (int ks = 0; ks < 25; ++ks) {
    const int k0 = ks * 32;
    __syncthreads();
    {  // stage x rows -> hi/lo bf16 planes (zero-pad K 784->800)
      unsigned int ph[8], pl[8];
      if (k0 + scb < 784) {
        const float4* px = (const float4*)(x + (size_t)(b0 + srow) * 784 + k0 + scb);
#pragma unroll
        for (int q = 0; q < 4; ++q) {
          float4 v = px[q];
          unsigned short hx = f2bf(v.x), hy = f2bf(v.y), hz = f2bf(v.z), hw = f2bf(v.w);
          unsigned short lx = f2bf(v.x - bf2f(hx)), ly = f2bf(v.y - bf2f(hy));
          unsigned short lz = f2bf(v.z - bf2f(hz)), lw = f2bf(v.w - bf2f(hw));
          ph[2 * q]     = (unsigned int)hx | ((unsigned int)hy << 16);
          ph[2 * q + 1] = (unsigned int)hz | ((unsigned int)hw << 16);
          pl[2 * q]     = (unsigned int)lx | ((unsigned int)ly << 16);
          pl[2 * q + 1] = (unsigned int)lz | ((unsigned int)lw << 16);
        }
      } else {
#pragma unroll
        for (int q = 0; q < 8; ++q) { ph[q] = 0u; pl[q] = 0u; }
      }
      uint4 a0 = {ph[0], ph[1], ph[2], ph[3]}, a1 = {ph[4], ph[5], ph[6], ph[7]};
      uint4 c0 = {pl[0], pl[1], pl[2], pl[3]}, c1 = {pl[4], pl[5], pl[6], pl[7]};
      *(uint4*)&xsh[srow * 40 + scb]     = a0;
      *(uint4*)&xsh[srow * 40 + scb + 8] = a1;
      *(uint4*)&xsl[srow * 40 + scb]     = c0;
      *(uint4*)&xsl[srow * 40 + scb + 8] = c1;
    }
    {  // stage W1 hi/lo: thread = output column
      const unsigned short* ph = W1h + (size_t)tid * 800 + k0;
      const unsigned short* pl = W1l + (size_t)tid * 800 + k0;
#pragma unroll
      for (int q = 0; q < 4; ++q) {
        *(uint4*)&wsh[tid * 40 + q * 8] = *(const uint4*)(ph + q * 8);
        *(uint4*)&wsl[tid * 40 + q * 8] = *(const uint4*)(pl + q * 8);
      }
    }
    __syncthreads();
    bf16x8 ah[2], al[2];
#pragma unroll
    for (int mt = 0; mt < 2; ++mt) {
      ah[mt] = *(const bf16x8*)&xsh[(w * 32 + mt * 16 + l15) * 40 + k8];
      al[mt] = *(const bf16x8*)&xsl[(w * 32 + mt * 16 + l15) * 40 + k8];
    }
#pragma unroll
    for (int nt = 0; nt < 16; ++nt) {
      bf16x8 bh = *(const bf16x8*)&wsh[(nt * 16 + l15) * 40 + k8];
      bf16x8 bl = *(const bf16x8*)&wsl[(nt * 16 + l15) * 40 + k8];
#pragma unroll
      for (int mt = 0; mt < 2; ++mt) {
        acc[mt][nt] = __builtin_amdgcn_mfma_f32_16x16x32_bf16(ah[mt], bh, acc[mt][nt], 0, 0, 0);
        acc[mt][nt] = __builtin_amdgcn_mfma_f32_16x16x32_bf16(al[mt], bh, acc[mt][nt], 0, 0, 0);
        acc[mt][nt] = __builtin_amdgcn_mfma_f32_16x16x32_bf16(ah[mt], bl, acc[mt][nt], 0, 0, 0);
      }
    }
  }

  // epilogue: relu(+b1), split hi/lo, pack into one u32 store per element
#pragma unroll
  for (int mt = 0; mt < 2; ++mt)
#pragma unroll
    for (int nt = 0; nt < 16; ++nt) {
      int col = nt * 16 + l15;
      float bb = b1s[col];
#pragma unroll
      for (int r = 0; r < 4; ++r) {
        int row = b0 + w * 32 + mt * 16 + lg4 * 4 + r;
        float v = acc[mt][nt][r] + bb;
        v = v > 0.f ? v : 0.f;
        unsigned short hi = f2bf(v);
        unsigned short lo = f2bf(v - bf2f(hi));
        H[(size_t)row * 256 + col] = (unsigned int)hi | ((unsigned int)lo << 16);
      }
    }
}

// ---------------- kB: GEMM2 + squash + u_hat + routing (all split-bf16) ------
// 16 samples/WG, wave = agent. u kept f32 in LDS scratch; u_hat kept f32,
// exchanged to routing threads via two agent-chunk LDS planes (union'd).
__global__ __launch_bounds__(256, 2) void kB(const unsigned int* __restrict__ H,
                                             const float* __restrict__ b2,
                                             const unsigned short* __restrict__ W2h,
                                             const unsigned short* __restrict__ W2l,
                                             const unsigned short* __restrict__ Wbh,
                                             const unsigned short* __restrict__ Wbl,
                                             float* __restrict__ out) {
  __shared__ float smem[2 * 16 * 330];  // 42,240 B union: u_scr (17,408 B) / uhat planes
  const int tid = threadIdx.x;
  const int a   = tid >> 6;   // wave = agent
  const int l   = tid & 63;
  const int l15 = l & 15;
  const int lg4 = l >> 4;
  const int k8  = lg4 * 8;
  const int b0  = blockIdx.x * 16;

  // ---- phase 1: GEMM2 (h hi/lo x W2 hi/lo, 3 terms) + b2 + squash -> u (f32 LDS)
  bf16x8 hh[2], hl[2];
#pragma unroll
  for (int kc = 0; kc < 2; ++kc) {
    const uint4* hp = (const uint4*)(H + (size_t)(b0 + l15) * 256 + a * 64 + kc * 32 + k8);
    uint4 q0 = hp[0], q1 = hp[1];
    unsigned int pw[8] = {q0.x, q0.y, q0.z, q0.w, q1.x, q1.y, q1.z, q1.w};
    BF8 vh, vl;
#pragma unroll
    for (int j = 0; j < 8; ++j) {
      vh.u[j] = (unsigned short)(pw[j] & 0xFFFFu);
      vl.u[j] = (unsigned short)(pw[j] >> 16);
    }
    hh[kc] = vh.b;
    hl[kc] = vl.b;
  }
  const f32x4 fz = {0.f, 0.f, 0.f, 0.f};
  f32x4 a2[4];
#pragma unroll
  for (int ot = 0; ot < 4; ++ot) a2[ot] = fz;
#pragma unroll
  for (int ot = 0; ot < 4; ++ot)
#pragma unroll
    for (int kc = 0; kc < 2; ++kc) {
      bf16x8 bh = *(const bf16x8*)(W2h + ((a * 64 + ot * 16 + l15) * 64 + kc * 32 + k8));
      bf16x8 bl = *(const bf16x8*)(W2l + ((a * 64 + ot * 16 + l15) * 64 + kc * 32 + k8));
      a2[ot] = __builtin_amdgcn_mfma_f32_16x16x32_bf16(hh[kc], bh, a2[ot], 0, 0, 0);
      a2[ot] = __builtin_amdgcn_mfma_f32_16x16x32_bf16(hl[kc], bh, a2[ot], 0, 0, 0);
      a2[ot] = __builtin_amdgcn_mfma_f32_16x16x32_bf16(hh[kc], bl, a2[ot], 0, 0, 0);
    }
  float b2v[4];
#pragma unroll
  for (int ot = 0; ot < 4; ++ot) b2v[ot] = b2[a * 64 + ot * 16 + l15];
#pragma unroll
  for (int r = 0; r < 4; ++r) {
    float up[4];
    float sq = 0.f;
#pragma unroll
    for (int ot = 0; ot < 4; ++ot) {
      float v = a2[ot][r] + b2v[ot];
      up[ot] = v;
      sq += v * v;
    }
    sq += __shfl_xor(sq, 1, 64);
    sq += __shfl_xor(sq, 2, 64);
    sq += __shfl_xor(sq, 4, 64);
    sq += __shfl_xor(sq, 8, 64);
    float scale = sq / ((1.f + sq) * sqrtf(sq + 1e-8f));
#pragma unroll
    for (int ot = 0; ot < 4; ++ot)
      smem[a * 1088 + (lg4 * 4 + r) * 68 + ot * 16 + l15] = scale * up[ot];
  }
  __syncthreads();

  // ---- phase 2: u A-frags (transpose read from LDS, split hi/lo in regs)
  bf16x8 uah[2], ual[2];
#pragma unroll
  for (int kc = 0; kc < 2; ++kc) {
    float4 f0 = *(const float4*)&smem[a * 1088 + l15 * 68 + kc * 32 + k8];
    float4 f1 = *(const float4*)&smem[a * 1088 + l15 * 68 + kc * 32 + k8 + 4];
    float vv[8] = {f0.x, f0.y, f0.z, f0.w, f1.x, f1.y, f1.z, f1.w};
    BF8 vh, vl;
#pragma unroll
    for (int j = 0; j < 8; ++j) {
      unsigned short hi = f2bf(vv[j]);
      vh.u[j] = hi;
      vl.u[j] = f2bf(vv[j] - bf2f(hi));
    }
    uah[kc] = vh.b;
    ual[kc] = vl.b;
  }
  __syncthreads();  // protect union before uhat writes

  // ---- phase 3: u_hat MFMA (u hi/lo x W hi/lo, 3 terms), f32 accum
  f32x4 au[20];
#pragma unroll
  for (int nt = 0; nt < 20; ++nt) au[nt] = fz;
#pragma unroll
  for (int nt = 0; nt < 20; ++nt)
#pragma unroll
    for (int kc = 0; kc < 2; ++kc) {
      bf16x8 bh = *(const bf16x8*)(Wbh + ((size_t)(a * 320 + nt * 16 + l15) * 64 + kc * 32 + k8));
      bf16x8 bl = *(const bf16x8*)(Wbl + ((size_t)(a * 320 + nt * 16 + l15) * 64 + kc * 32 + k8));
      au[nt] = __builtin_amdgcn_mfma_f32_16x16x32_bf16(uah[kc], bh, au[nt], 0, 0, 0);
      au[nt] = __builtin_amdgcn_mfma_f32_16x16x32_bf16(ual[kc], bh, au[nt], 0, 0, 0);
      au[nt] = __builtin_amdgcn_mfma_f32_16x16x32_bf16(uah[kc], bl, au[nt], 0, 0, 0);
    }

  // ---- phase 4: two-chunk f32 exchange into routing registers
  const int sid = tid >> 4;
  const int li  = tid & 15;
  float2 uhr[4][10];
  if (a < 2) {
#pragma unroll
    for (int nt = 0; nt < 20; ++nt)
#pragma unroll
      for (int r = 0; r < 4; ++r)
        smem[a * 5280 + (lg4 * 4 + r) * 330 + nt * 16 + l15] = au[nt][r];
  }
  __syncthreads();
#pragma unroll
  for (int s = 0; s < 2; ++s)
#pragma unroll
    for (int j = 0; j < 10; ++j)
      uhr[s][j] = *(const float2*)&smem[s * 5280 + sid * 330 + j * 32 + 2 * li];
  __syncthreads();
  if (a >= 2) {
#pragma unroll
    for (int nt = 0; nt < 20; ++nt)
#pragma unroll
      for (int r = 0; r < 4; ++r)
        smem[(a - 2) * 5280 + (lg4 * 4 + r) * 330 + nt * 16 + l15] = au[nt][r];
  }
  __syncthreads();
#pragma unroll
  for (int s = 0; s < 2; ++s)
#pragma unroll
    for (int j = 0; j < 10; ++j)
      uhr[2 + s][j] = *(const float2*)&smem[s * 5280 + sid * 330 + j * 32 + 2 * li];

  // ---- phase 5: dynamic routing (3 iters) fully in registers
  float lgt[4][10];
#pragma unroll
  for (int aa = 0; aa < 4; ++aa)
#pragma unroll
    for (int j = 0; j < 10; ++j) lgt[aa][j] = 0.f;

  for (int it = 0; it < 3; ++it) {
    float cc[4][10];
#pragma unroll
    for (int aa = 0; aa < 4; ++aa) {
      float m = lgt[aa][0];
#pragma unroll
      for (int j = 1; j < 10; ++j) m = fmaxf(m, lgt[aa][j]);
      float s = 0.f;
#pragma unroll
      for (int j = 0; j < 10; ++j) { float e = __expf(lgt[aa][j] - m); cc[aa][j] = e; s += e; }
      float inv = 1.f / s;
#pragma unroll
      for (int j = 0; j < 10; ++j) cc[aa][j] *= inv;
    }
#pragma unroll
    for (int j = 0; j < 10; ++j) {
      float s0 = 0.f, s1 = 0.f;
#pragma unroll
      for (int aa = 0; aa < 4; ++aa) {
        s0 += cc[aa][j] * uhr[aa][j].x;
        s1 += cc[aa][j] * uhr[aa][j].y;
      }
      float sq = s0 * s0 + s1 * s1;
      sq += __shfl_xor(sq, 1, 64);
      sq += __shfl_xor(sq, 2, 64);
      sq += __shfl_xor(sq, 4, 64);
      sq += __shfl_xor(sq, 8, 64);
      float scale = sq / ((1.f + sq) * sqrtf(sq + 1e-8f));
      float v0 = scale * s0, v1 = scale * s1;
      if (it < 2) {
#pragma unroll
        for (int aa = 0; aa < 4; ++aa) {
          float ag = uhr[aa][j].x * v0 + uhr[aa][j].y * v1;
          ag += __shfl_xor(ag, 1, 64);
          ag += __shfl_xor(ag, 2, 64);
          ag += __shfl_xor(ag, 4, 64);
          ag += __shfl_xor(ag, 8, 64);
          lgt[aa][j] += ag;
        }
      } else {
        float2 vv = {v0, v1};
        *(float2*)(out + (size_t)(b0 + sid) * 320 + j * 32 + 2 * li) = vv;
      }
    }
  }
}

extern "C" void kernel_launch(void* const* d_in, const int* in_sizes, int n_in,
                              void* d_out, int out_size, void* d_ws, size_t ws_size,
                              hipStream_t stream) {
  const float* x  = (const float*)d_in[0];
  const float* W1 = (const float*)d_in[1];
  const float* b1 = (const float*)d_in[2];
  const float* W2 = (const float*)d_in[3];
  const float* b2 = (const float*)d_in[4];
  const float* W  = (const float*)d_in[5];

  unsigned short* wsb = (unsigned short*)d_ws;
  unsigned short* W1h = wsb;                 // 204800
  unsigned short* W1l = wsb + 204800;        // 204800
  unsigned short* W2h = wsb + 409600;        // 16384
  unsigned short* W2l = wsb + 425984;        // 16384
  unsigned short* Wbh = wsb + 442368;        // 81920
  unsigned short* Wbl = wsb + 524288;        // 81920
  unsigned int*   H   = (unsigned int*)(wsb + 606208);  // 32768*256 u32
  float* out = (float*)d_out;

  kprep<<<800, 256, 0, stream>>>(W1, W2, W, W1h, W1l, W2h, W2l, Wbh, Wbl);
  kA<<<256, 256, 0, stream>>>(x, b1, W1h, W1l, H);
  kB<<<2048, 256, 0, stream>>>(H, b2, W2h, W2l, Wbh, Wbl, out);
}

// Round 4
// 198.393 us; speedup vs baseline: 1.2233x; 1.2233x over previous
//
#include <hip/hip_runtime.h>

typedef __bf16 bf16_t;
typedef bf16_t bf16x8 __attribute__((ext_vector_type(8)));
typedef unsigned short u16x8 __attribute__((ext_vector_type(8)));
typedef float f32x4 __attribute__((ext_vector_type(4)));

union BF8 { u16x8 u; bf16x8 b; };

__device__ __forceinline__ unsigned short f2bf(float f) {
  unsigned int u = __float_as_uint(f);
  unsigned int r = (u + 0x7FFFu + ((u >> 16) & 1u)) >> 16;
  return (unsigned short)r;
}
__device__ __forceinline__ float bf2f(unsigned short s) {
  return __uint_as_float(((unsigned int)s) << 16);
}

// ---------------- prep: all weights -> bf16 hi/lo planes ---------------------
__global__ __launch_bounds__(256) void kprep(const float* __restrict__ W1,
                                             const float* __restrict__ W2,
                                             const float* __restrict__ W,
                                             unsigned short* __restrict__ W1h,
                                             unsigned short* __restrict__ W1l,
                                             unsigned short* __restrict__ W2h,
                                             unsigned short* __restrict__ W2l,
                                             unsigned short* __restrict__ Wbh,
                                             unsigned short* __restrict__ Wbl) {
  int idx = blockIdx.x * 256 + threadIdx.x;
  if (idx < 204800) {
    int c = idx / 800, k = idx - c * 800;
    int a = c >> 6, o = c & 63;
    float v = (k < 784) ? W1[(a * 784 + k) * 64 + o] : 0.f;
    unsigned short hi = f2bf(v);
    W1h[idx] = hi;
    W1l[idx] = f2bf(v - bf2f(hi));
  }
  if (idx < 16384) {
    int a = idx >> 12, o = (idx >> 6) & 63, k = idx & 63;
    float v = W2[(a * 64 + k) * 64 + o];
    unsigned short hi = f2bf(v);
    W2h[idx] = hi;
    W2l[idx] = f2bf(v - bf2f(hi));
  }
  if (idx < 81920) {
    float v = W[idx];
    unsigned short hi = f2bf(v);
    Wbh[idx] = hi;
    Wbl[idx] = f2bf(v - bf2f(hi));
  }
}

// ---------------- kA: h = relu(x@W1 + b1), split-bf16, -> packed u32 ---------
__global__ __launch_bounds__(256, 2) void kA(const float* __restrict__ x,
                                             const float* __restrict__ b1,
                                             const unsigned short* __restrict__ W1h,
                                             const unsigned short* __restrict__ W1l,
                                             unsigned int* __restrict__ H) {
  __shared__ unsigned short xsh[128 * 40];
  __shared__ unsigned short xsl[128 * 40];
  __shared__ unsigned short wsh[256 * 40];
  __shared__ unsigned short wsl[256 * 40];
  __shared__ float b1s[256];
  const int tid = threadIdx.x;
  const int w   = tid >> 6;
  const int l   = tid & 63;
  const int l15 = l & 15;
  const int lg4 = l >> 4;
  const int k8  = lg4 * 8;
  const int b0  = blockIdx.x * 128;

  b1s[tid] = b1[tid];

  const f32x4 fz = {0.f, 0.f, 0.f, 0.f};
  f32x4 acc[2][16];
#pragma unroll
  for (int m = 0; m < 2; ++m)
#pragma unroll
    for (int n = 0; n < 16; ++n) acc[m][n] = fz;

  const int srow = tid >> 1;
  const int scb  = (tid & 1) * 16;

  for (int ks = 0; ks < 25; ++ks) {
    const int k0 = ks * 32;
    __syncthreads();
    {
      unsigned int ph[8], pl[8];
      if (k0 + scb < 784) {
        const float4* px = (const float4*)(x + (size_t)(b0 + srow) * 784 + k0 + scb);
#pragma unroll
        for (int q = 0; q < 4; ++q) {
          float4 v = px[q];
          unsigned short hx = f2bf(v.x), hy = f2bf(v.y), hz = f2bf(v.z), hw = f2bf(v.w);
          unsigned short lx = f2bf(v.x - bf2f(hx)), ly = f2bf(v.y - bf2f(hy));
          unsigned short lz = f2bf(v.z - bf2f(hz)), lw = f2bf(v.w - bf2f(hw));
          ph[2 * q]     = (unsigned int)hx | ((unsigned int)hy << 16);
          ph[2 * q + 1] = (unsigned int)hz | ((unsigned int)hw << 16);
          pl[2 * q]     = (unsigned int)lx | ((unsigned int)ly << 16);
          pl[2 * q + 1] = (unsigned int)lz | ((unsigned int)lw << 16);
        }
      } else {
#pragma unroll
        for (int q = 0; q < 8; ++q) { ph[q] = 0u; pl[q] = 0u; }
      }
      uint4 a0 = {ph[0], ph[1], ph[2], ph[3]}, a1 = {ph[4], ph[5], ph[6], ph[7]};
      uint4 c0 = {pl[0], pl[1], pl[2], pl[3]}, c1 = {pl[4], pl[5], pl[6], pl[7]};
      *(uint4*)&xsh[srow * 40 + scb]     = a0;
      *(uint4*)&xsh[srow * 40 + scb + 8] = a1;
      *(uint4*)&xsl[srow * 40 + scb]     = c0;
      *(uint4*)&xsl[srow * 40 + scb + 8] = c1;
    }
    {
      const unsigned short* ph = W1h + (size_t)tid * 800 + k0;
      const unsigned short* pl = W1l + (size_t)tid * 800 + k0;
#pragma unroll
      for (int q = 0; q < 4; ++q) {
        *(uint4*)&wsh[tid * 40 + q * 8] = *(const uint4*)(ph + q * 8);
        *(uint4*)&wsl[tid * 40 + q * 8] = *(const uint4*)(pl + q * 8);
      }
    }
    __syncthreads();
    bf16x8 ah[2], al[2];
#pragma unroll
    for (int mt = 0; mt < 2; ++mt) {
      ah[mt] = *(const bf16x8*)&xsh[(w * 32 + mt * 16 + l15) * 40 + k8];
      al[mt] = *(const bf16x8*)&xsl[(w * 32 + mt * 16 + l15) * 40 + k8];
    }
#pragma unroll
    for (int nt = 0; nt < 16; ++nt) {
      bf16x8 bh = *(const bf16x8*)&wsh[(nt * 16 + l15) * 40 + k8];
      bf16x8 bl = *(const bf16x8*)&wsl[(nt * 16 + l15) * 40 + k8];
#pragma unroll
      for (int mt = 0; mt < 2; ++mt) {
        acc[mt][nt] = __builtin_amdgcn_mfma_f32_16x16x32_bf16(ah[mt], bh, acc[mt][nt], 0, 0, 0);
        acc[mt][nt] = __builtin_amdgcn_mfma_f32_16x16x32_bf16(al[mt], bh, acc[mt][nt], 0, 0, 0);
        acc[mt][nt] = __builtin_amdgcn_mfma_f32_16x16x32_bf16(ah[mt], bl, acc[mt][nt], 0, 0, 0);
      }
    }
  }

#pragma unroll
  for (int mt = 0; mt < 2; ++mt)
#pragma unroll
    for (int nt = 0; nt < 16; ++nt) {
      int col = nt * 16 + l15;
      float bb = b1s[col];
#pragma unroll
      for (int r = 0; r < 4; ++r) {
        int row = b0 + w * 32 + mt * 16 + lg4 * 4 + r;
        float v = acc[mt][nt][r] + bb;
        v = v > 0.f ? v : 0.f;
        unsigned short hi = f2bf(v);
        unsigned short lo = f2bf(v - bf2f(hi));
        H[(size_t)row * 256 + col] = (unsigned int)hi | ((unsigned int)lo << 16);
      }
    }
}

// ---------------- kB: GEMM2 + squash + u_hat + register-Gram routing ---------
// 16 samples/WG, wave = agent. After u_hat MFMA, two i-half LDS exchanges put
// u_hat[s][*][j][*] fully into routing-thread registers (ua[2][4][16]); Gram,
// 3 routing iterations, v-combine and the store are then register-local
// (only softmax denominators cross lanes). No atomics, no extra LDS planes.
__global__ __launch_bounds__(256, 2) void kB(const unsigned int* __restrict__ H,
                                             const float* __restrict__ b2,
                                             const unsigned short* __restrict__ W2h,
                                             const unsigned short* __restrict__ W2l,
                                             const unsigned short* __restrict__ Wbh,
                                             const unsigned short* __restrict__ Wbl,
                                             float* __restrict__ out) {
  // union: u_scr [0,4352) f32 (phases 1-2) / uc [0,13056) f32 = [64 rows][204]
  // (row = a*16+s; within row: q*20 + i', 16B-aligned q-blocks, pad 4)
  __shared__ float smem[13056];
  const int tid = threadIdx.x;
  const int a   = tid >> 6;   // wave = agent
  const int l   = tid & 63;
  const int l15 = l & 15;
  const int lg4 = l >> 4;
  const int k8  = lg4 * 8;
  const int b0  = blockIdx.x * 16;

  // ---- phase 1: GEMM2 (split-bf16) + b2 + squash -> u (f32 in u_scr)
  bf16x8 hh[2], hl[2];
#pragma unroll
  for (int kc = 0; kc < 2; ++kc) {
    const uint4* hp = (const uint4*)(H + (size_t)(b0 + l15) * 256 + a * 64 + kc * 32 + k8);
    uint4 q0 = hp[0], q1 = hp[1];
    unsigned int pw[8] = {q0.x, q0.y, q0.z, q0.w, q1.x, q1.y, q1.z, q1.w};
    BF8 vh, vl;
#pragma unroll
    for (int j = 0; j < 8; ++j) {
      vh.u[j] = (unsigned short)(pw[j] & 0xFFFFu);
      vl.u[j] = (unsigned short)(pw[j] >> 16);
    }
    hh[kc] = vh.b;
    hl[kc] = vl.b;
  }
  const f32x4 fz = {0.f, 0.f, 0.f, 0.f};
  f32x4 a2[4];
#pragma unroll
  for (int ot = 0; ot < 4; ++ot) a2[ot] = fz;
#pragma unroll
  for (int ot = 0; ot < 4; ++ot)
#pragma unroll
    for (int kc = 0; kc < 2; ++kc) {
      bf16x8 bh = *(const bf16x8*)(W2h + ((a * 64 + ot * 16 + l15) * 64 + kc * 32 + k8));
      bf16x8 bl = *(const bf16x8*)(W2l + ((a * 64 + ot * 16 + l15) * 64 + kc * 32 + k8));
      a2[ot] = __builtin_amdgcn_mfma_f32_16x16x32_bf16(hh[kc], bh, a2[ot], 0, 0, 0);
      a2[ot] = __builtin_amdgcn_mfma_f32_16x16x32_bf16(hl[kc], bh, a2[ot], 0, 0, 0);
      a2[ot] = __builtin_amdgcn_mfma_f32_16x16x32_bf16(hh[kc], bl, a2[ot], 0, 0, 0);
    }
  float b2v[4];
#pragma unroll
  for (int ot = 0; ot < 4; ++ot) b2v[ot] = b2[a * 64 + ot * 16 + l15];
#pragma unroll
  for (int r = 0; r < 4; ++r) {
    float up[4];
    float sq = 0.f;
#pragma unroll
    for (int ot = 0; ot < 4; ++ot) {
      float v = a2[ot][r] + b2v[ot];
      up[ot] = v;
      sq += v * v;
    }
    sq += __shfl_xor(sq, 1, 64);
    sq += __shfl_xor(sq, 2, 64);
    sq += __shfl_xor(sq, 4, 64);
    sq += __shfl_xor(sq, 8, 64);
    float scale = sq / ((1.f + sq) * sqrtf(sq + 1e-8f));
#pragma unroll
    for (int ot = 0; ot < 4; ++ot)
      smem[a * 1088 + (lg4 * 4 + r) * 68 + ot * 16 + l15] = scale * up[ot];
  }
  __syncthreads();

  // ---- phase 2: u A-frags (transpose read, split hi/lo)
  bf16x8 uah[2], ual[2];
#pragma unroll
  for (int kc = 0; kc < 2; ++kc) {
    float4 f0 = *(const float4*)&smem[a * 1088 + l15 * 68 + kc * 32 + k8];
    float4 f1 = *(const float4*)&smem[a * 1088 + l15 * 68 + kc * 32 + k8 + 4];
    float vv[8] = {f0.x, f0.y, f0.z, f0.w, f1.x, f1.y, f1.z, f1.w};
    BF8 vh, vl;
#pragma unroll
    for (int j = 0; j < 8; ++j) {
      unsigned short hi = f2bf(vv[j]);
      vh.u[j] = hi;
      vl.u[j] = f2bf(vv[j] - bf2f(hi));
    }
    uah[kc] = vh.b;
    ual[kc] = vl.b;
  }
  __syncthreads();  // u_scr dead; uc overlays it

  // ---- phase 3: u_hat MFMA (3-term split), f32 accum in registers
  f32x4 au[20];
#pragma unroll
  for (int nt = 0; nt < 20; ++nt) au[nt] = fz;
#pragma unroll
  for (int nt = 0; nt < 20; ++nt)
#pragma unroll
    for (int kc = 0; kc < 2; ++kc) {
      bf16x8 bh = *(const bf16x8*)(Wbh + ((size_t)(a * 320 + nt * 16 + l15) * 64 + kc * 32 + k8));
      bf16x8 bl = *(const bf16x8*)(Wbl + ((size_t)(a * 320 + nt * 16 + l15) * 64 + kc * 32 + k8));
      au[nt] = __builtin_amdgcn_mfma_f32_16x16x32_bf16(uah[kc], bh, au[nt], 0, 0, 0);
      au[nt] = __builtin_amdgcn_mfma_f32_16x16x32_bf16(ual[kc], bh, au[nt], 0, 0, 0);
      au[nt] = __builtin_amdgcn_mfma_f32_16x16x32_bf16(uah[kc], bl, au[nt], 0, 0, 0);
    }

  // ---- phase 4: two i-half exchanges -> ua[2][4][16] registers
  const int sid   = tid >> 4;
  const int jraw  = tid & 15;
  const bool jact = (jraw < 10);
  const int jj    = jact ? jraw : 9;
  float ua[2][4][16];

#pragma unroll
  for (int half = 0; half < 2; ++half) {
#pragma unroll
    for (int q = 0; q < 10; ++q)
#pragma unroll
      for (int r = 0; r < 4; ++r)
        smem[(a * 16 + lg4 * 4 + r) * 204 + q * 20 + l15] = au[q * 2 + half][r];
    __syncthreads();
#pragma unroll
    for (int ag = 0; ag < 4; ++ag)
#pragma unroll
      for (int qq = 0; qq < 4; ++qq) {
        float4 f = *(const float4*)&smem[(ag * 16 + sid) * 204 + jj * 20 + qq * 4];
        ua[half][ag][qq * 4 + 0] = f.x;
        ua[half][ag][qq * 4 + 1] = f.y;
        ua[half][ag][qq * 4 + 2] = f.z;
        ua[half][ag][qq * 4 + 3] = f.w;
      }
    if (half == 0) __syncthreads();  // protect half-1 overwrite
  }

  // ---- phase 5: register Gram + 3 routing iterations
  float Gp[10];
#pragma unroll
  for (int p = 0; p < 10; ++p) Gp[p] = 0.f;
#pragma unroll
  for (int half = 0; half < 2; ++half)
#pragma unroll
    for (int i = 0; i < 16; ++i) {
      float v0 = ua[half][0][i], v1 = ua[half][1][i];
      float v2 = ua[half][2][i], v3 = ua[half][3][i];
      Gp[0] += v0 * v0; Gp[1] += v0 * v1; Gp[2] += v0 * v2; Gp[3] += v0 * v3;
      Gp[4] += v1 * v1; Gp[5] += v1 * v2; Gp[6] += v1 * v3;
      Gp[7] += v2 * v2; Gp[8] += v2 * v3;
      Gp[9] += v3 * v3;
    }

  float cf0 = 0.f, cf1 = 0.f, cf2 = 0.f, cf3 = 0.f;
  {
    float lg0 = 0.f, lg1 = 0.f, lg2 = 0.f, lg3 = 0.f;
#pragma unroll
    for (int it = 0; it < 3; ++it) {
      float e0 = jact ? __expf(lg0) : 0.f;
      float e1 = jact ? __expf(lg1) : 0.f;
      float e2 = jact ? __expf(lg2) : 0.f;
      float e3 = jact ? __expf(lg3) : 0.f;
      float S0 = e0, S1 = e1, S2 = e2, S3 = e3;
#pragma unroll
      for (int m = 1; m <= 8; m <<= 1) {
        S0 += __shfl_xor(S0, m, 16);
        S1 += __shfl_xor(S1, m, 16);
        S2 += __shfl_xor(S2, m, 16);
        S3 += __shfl_xor(S3, m, 16);
      }
      float c0 = e0 / S0, c1 = e1 / S1, c2 = e2 / S2, c3 = e3 / S3;
      float t0 = c0 * Gp[0] + c1 * Gp[1] + c2 * Gp[2] + c3 * Gp[3];
      float t1 = c0 * Gp[1] + c1 * Gp[4] + c2 * Gp[5] + c3 * Gp[6];
      float t2 = c0 * Gp[2] + c1 * Gp[5] + c2 * Gp[7] + c3 * Gp[8];
      float t3 = c0 * Gp[3] + c1 * Gp[6] + c2 * Gp[8] + c3 * Gp[9];
      float sq = c0 * t0 + c1 * t1 + c2 * t2 + c3 * t3;
      float scale = sq / ((1.f + sq) * sqrtf(sq + 1e-8f));
      if (it < 2) {
        lg0 += scale * t0;
        lg1 += scale * t1;
        lg2 += scale * t2;
        lg3 += scale * t3;
      } else {
        cf0 = scale * c0;
        cf1 = scale * c1;
        cf2 = scale * c2;
        cf3 = scale * c3;
      }
    }
  }

  // ---- phase 6: v = sum_a cf_a * ua, direct coalesced store
  if (jact) {
    float* po = out + (size_t)(b0 + sid) * 320 + jraw * 32;
#pragma unroll
    for (int q = 0; q < 8; ++q) {
      float st[4];
#pragma unroll
      for (int e = 0; e < 4; ++e) {
        int i = q * 4 + e;
        int ih = i >> 4, il = i & 15;
        st[e] = cf0 * ua[ih][0][il] + cf1 * ua[ih][1][il] +
                cf2 * ua[ih][2][il] + cf3 * ua[ih][3][il];
      }
      float4 v4 = {st[0], st[1], st[2], st[3]};
      *(float4*)(po + q * 4) = v4;
    }
  }
}

extern "C" void kernel_launch(void* const* d_in, const int* in_sizes, int n_in,
                              void* d_out, int out_size, void* d_ws, size_t ws_size,
                              hipStream_t stream) {
  const float* x  = (const float*)d_in[0];
  const float* W1 = (const float*)d_in[1];
  const float* b1 = (const float*)d_in[2];
  const float* W2 = (const float*)d_in[3];
  const float* b2 = (const float*)d_in[4];
  const float* W  = (const float*)d_in[5];

  unsigned short* wsb = (unsigned short*)d_ws;
  unsigned short* W1h = wsb;                 // 204800
  unsigned short* W1l = wsb + 204800;        // 204800
  unsigned short* W2h = wsb + 409600;        // 16384
  unsigned short* W2l = wsb + 425984;        // 16384
  unsigned short* Wbh = wsb + 442368;        // 81920
  unsigned short* Wbl = wsb + 524288;        // 81920
  unsigned int*   H   = (unsigned int*)(wsb + 606208);  // 32768*256 u32
  float* out = (float*)d_out;

  kprep<<<800, 256, 0, stream>>>(W1, W2, W, W1h, W1l, W2h, W2l, Wbh, Wbl);
  kA<<<256, 256, 0, stream>>>(x, b1, W1h, W1l, H);
  kB<<<2048, 256, 0, stream>>>(H, b2, W2h, W2l, Wbh, Wbl, out);
}

// Round 5
// 198.018 us; speedup vs baseline: 1.2256x; 1.0019x over previous
//
#include <hip/hip_runtime.h>

typedef __bf16 bf16_t;
typedef bf16_t bf16x8 __attribute__((ext_vector_type(8)));
typedef unsigned short u16x8 __attribute__((ext_vector_type(8)));
typedef float f32x4 __attribute__((ext_vector_type(4)));

union BF8 { u16x8 u; bf16x8 b; };

__device__ __forceinline__ unsigned short f2bf(float f) {
  unsigned int u = __float_as_uint(f);
  unsigned int r = (u + 0x7FFFu + ((u >> 16) & 1u)) >> 16;
  return (unsigned short)r;
}
__device__ __forceinline__ float bf2f(unsigned short s) {
  return __uint_as_float(((unsigned int)s) << 16);
}

// ---------------- prep: all weights -> bf16 hi/lo planes ---------------------
__global__ __launch_bounds__(256) void kprep(const float* __restrict__ W1,
                                             const float* __restrict__ W2,
                                             const float* __restrict__ W,
                                             unsigned short* __restrict__ W1h,
                                             unsigned short* __restrict__ W1l,
                                             unsigned short* __restrict__ W2h,
                                             unsigned short* __restrict__ W2l,
                                             unsigned short* __restrict__ Wbh,
                                             unsigned short* __restrict__ Wbl) {
  int idx = blockIdx.x * 256 + threadIdx.x;
  if (idx < 204800) {
    int c = idx / 800, k = idx - c * 800;
    int a = c >> 6, o = c & 63;
    float v = (k < 784) ? W1[(a * 784 + k) * 64 + o] : 0.f;
    unsigned short hi = f2bf(v);
    W1h[idx] = hi;
    W1l[idx] = f2bf(v - bf2f(hi));
  }
  if (idx < 16384) {
    int a = idx >> 12, o = (idx >> 6) & 63, k = idx & 63;
    float v = W2[(a * 64 + k) * 64 + o];
    unsigned short hi = f2bf(v);
    W2h[idx] = hi;
    W2l[idx] = f2bf(v - bf2f(hi));
  }
  if (idx < 81920) {
    float v = W[idx];
    unsigned short hi = f2bf(v);
    Wbh[idx] = hi;
    Wbl[idx] = f2bf(v - bf2f(hi));
  }
}

// ---------------- kA: h = relu(x@W1 + b1), split-bf16, -> packed u32 ---------
__global__ __launch_bounds__(256, 2) void kA(const float* __restrict__ x,
                                             const float* __restrict__ b1,
                                             const unsigned short* __restrict__ W1h,
                                             const unsigned short* __restrict__ W1l,
                                             unsigned int* __restrict__ H) {
  __shared__ unsigned short xsh[128 * 40];
  __shared__ unsigned short xsl[128 * 40];
  __shared__ unsigned short wsh[256 * 40];
  __shared__ unsigned short wsl[256 * 40];
  __shared__ float b1s[256];
  const int tid = threadIdx.x;
  const int w   = tid >> 6;
  const int l   = tid & 63;
  const int l15 = l & 15;
  const int lg4 = l >> 4;
  const int k8  = lg4 * 8;
  const int b0  = blockIdx.x * 128;

  b1s[tid] = b1[tid];

  const f32x4 fz = {0.f, 0.f, 0.f, 0.f};
  f32x4 acc[2][16];
#pragma unroll
  for (int m = 0; m < 2; ++m)
#pragma unroll
    for (int n = 0; n < 16; ++n) acc[m][n] = fz;

  const int srow = tid >> 1;
  const int scb  = (tid & 1) * 16;

  for (int ks = 0; ks < 25; ++ks) {
    const int k0 = ks * 32;
    __syncthreads();
    {
      unsigned int ph[8], pl[8];
      if (k0 + scb < 784) {
        const float4* px = (const float4*)(x + (size_t)(b0 + srow) * 784 + k0 + scb);
#pragma unroll
        for (int q = 0; q < 4; ++q) {
          float4 v = px[q];
          unsigned short hx = f2bf(v.x), hy = f2bf(v.y), hz = f2bf(v.z), hw = f2bf(v.w);
          unsigned short lx = f2bf(v.x - bf2f(hx)), ly = f2bf(v.y - bf2f(hy));
          unsigned short lz = f2bf(v.z - bf2f(hz)), lw = f2bf(v.w - bf2f(hw));
          ph[2 * q]     = (unsigned int)hx | ((unsigned int)hy << 16);
          ph[2 * q + 1] = (unsigned int)hz | ((unsigned int)hw << 16);
          pl[2 * q]     = (unsigned int)lx | ((unsigned int)ly << 16);
          pl[2 * q + 1] = (unsigned int)lz | ((unsigned int)lw << 16);
        }
      } else {
#pragma unroll
        for (int q = 0; q < 8; ++q) { ph[q] = 0u; pl[q] = 0u; }
      }
      uint4 a0 = {ph[0], ph[1], ph[2], ph[3]}, a1 = {ph[4], ph[5], ph[6], ph[7]};
      uint4 c0 = {pl[0], pl[1], pl[2], pl[3]}, c1 = {pl[4], pl[5], pl[6], pl[7]};
      *(uint4*)&xsh[srow * 40 + scb]     = a0;
      *(uint4*)&xsh[srow * 40 + scb + 8] = a1;
      *(uint4*)&xsl[srow * 40 + scb]     = c0;
      *(uint4*)&xsl[srow * 40 + scb + 8] = c1;
    }
    {
      const unsigned short* ph = W1h + (size_t)tid * 800 + k0;
      const unsigned short* pl = W1l + (size_t)tid * 800 + k0;
#pragma unroll
      for (int q = 0; q < 4; ++q) {
        *(uint4*)&wsh[tid * 40 + q * 8] = *(const uint4*)(ph + q * 8);
        *(uint4*)&wsl[tid * 40 + q * 8] = *(const uint4*)(pl + q * 8);
      }
    }
    __syncthreads();
    bf16x8 ah[2], al[2];
#pragma unroll
    for (int mt = 0; mt < 2; ++mt) {
      ah[mt] = *(const bf16x8*)&xsh[(w * 32 + mt * 16 + l15) * 40 + k8];
      al[mt] = *(const bf16x8*)&xsl[(w * 32 + mt * 16 + l15) * 40 + k8];
    }
#pragma unroll
    for (int nt = 0; nt < 16; ++nt) {
      bf16x8 bh = *(const bf16x8*)&wsh[(nt * 16 + l15) * 40 + k8];
      bf16x8 bl = *(const bf16x8*)&wsl[(nt * 16 + l15) * 40 + k8];
#pragma unroll
      for (int mt = 0; mt < 2; ++mt) {
        acc[mt][nt] = __builtin_amdgcn_mfma_f32_16x16x32_bf16(ah[mt], bh, acc[mt][nt], 0, 0, 0);
        acc[mt][nt] = __builtin_amdgcn_mfma_f32_16x16x32_bf16(al[mt], bh, acc[mt][nt], 0, 0, 0);
        acc[mt][nt] = __builtin_amdgcn_mfma_f32_16x16x32_bf16(ah[mt], bl, acc[mt][nt], 0, 0, 0);
      }
    }
  }

#pragma unroll
  for (int mt = 0; mt < 2; ++mt)
#pragma unroll
    for (int nt = 0; nt < 16; ++nt) {
      int col = nt * 16 + l15;
      float bb = b1s[col];
#pragma unroll
      for (int r = 0; r < 4; ++r) {
        int row = b0 + w * 32 + mt * 16 + lg4 * 4 + r;
        float v = acc[mt][nt][r] + bb;
        v = v > 0.f ? v : 0.f;
        unsigned short hi = f2bf(v);
        unsigned short lo = f2bf(v - bf2f(hi));
        H[(size_t)row * 256 + col] = (unsigned int)hi | ((unsigned int)lo << 16);
      }
    }
}

// ---------------- kB: GEMM2 + squash + u_hat + streaming-Gram routing -------
// 16 samples/WG, wave = agent. u_hat lives ONLY in MFMA registers (au[20]);
// routing threads stream it from the LDS exchange plane 16 floats at a time
// (Gram pass + v pass) -- no big per-thread arrays, no scratch spill.
__global__ __launch_bounds__(256, 3) void kB(const unsigned int* __restrict__ H,
                                             const float* __restrict__ b2,
                                             const unsigned short* __restrict__ W2h,
                                             const unsigned short* __restrict__ W2l,
                                             const unsigned short* __restrict__ Wbh,
                                             const unsigned short* __restrict__ Wbl,
                                             float* __restrict__ out) {
  // union: u_scr [0,4352) f32 (phases 1-2) / uc [0,13056) f32 = [64 rows][204]
  // (row = a*16+s; within row: j*20 + i', 16B-aligned j-blocks, pad 4)
  __shared__ float smem[13056];
  const int tid = threadIdx.x;
  const int a   = tid >> 6;   // wave = agent
  const int l   = tid & 63;
  const int l15 = l & 15;
  const int lg4 = l >> 4;
  const int k8  = lg4 * 8;
  const int b0  = blockIdx.x * 16;

  // ---- phase 1: GEMM2 (split-bf16) + b2 + squash -> u (f32 in u_scr)
  bf16x8 hh[2], hl[2];
#pragma unroll
  for (int kc = 0; kc < 2; ++kc) {
    const uint4* hp = (const uint4*)(H + (size_t)(b0 + l15) * 256 + a * 64 + kc * 32 + k8);
    uint4 q0 = hp[0], q1 = hp[1];
    unsigned int pw[8] = {q0.x, q0.y, q0.z, q0.w, q1.x, q1.y, q1.z, q1.w};
    BF8 vh, vl;
#pragma unroll
    for (int j = 0; j < 8; ++j) {
      vh.u[j] = (unsigned short)(pw[j] & 0xFFFFu);
      vl.u[j] = (unsigned short)(pw[j] >> 16);
    }
    hh[kc] = vh.b;
    hl[kc] = vl.b;
  }
  const f32x4 fz = {0.f, 0.f, 0.f, 0.f};
  f32x4 a2[4];
#pragma unroll
  for (int ot = 0; ot < 4; ++ot) a2[ot] = fz;
#pragma unroll
  for (int ot = 0; ot < 4; ++ot)
#pragma unroll
    for (int kc = 0; kc < 2; ++kc) {
      bf16x8 bh = *(const bf16x8*)(W2h + ((a * 64 + ot * 16 + l15) * 64 + kc * 32 + k8));
      bf16x8 bl = *(const bf16x8*)(W2l + ((a * 64 + ot * 16 + l15) * 64 + kc * 32 + k8));
      a2[ot] = __builtin_amdgcn_mfma_f32_16x16x32_bf16(hh[kc], bh, a2[ot], 0, 0, 0);
      a2[ot] = __builtin_amdgcn_mfma_f32_16x16x32_bf16(hl[kc], bh, a2[ot], 0, 0, 0);
      a2[ot] = __builtin_amdgcn_mfma_f32_16x16x32_bf16(hh[kc], bl, a2[ot], 0, 0, 0);
    }
  float b2v[4];
#pragma unroll
  for (int ot = 0; ot < 4; ++ot) b2v[ot] = b2[a * 64 + ot * 16 + l15];
#pragma unroll
  for (int r = 0; r < 4; ++r) {
    float up[4];
    float sq = 0.f;
#pragma unroll
    for (int ot = 0; ot < 4; ++ot) {
      float v = a2[ot][r] + b2v[ot];
      up[ot] = v;
      sq += v * v;
    }
    sq += __shfl_xor(sq, 1, 64);
    sq += __shfl_xor(sq, 2, 64);
    sq += __shfl_xor(sq, 4, 64);
    sq += __shfl_xor(sq, 8, 64);
    float scale = sq / ((1.f + sq) * sqrtf(sq + 1e-8f));
#pragma unroll
    for (int ot = 0; ot < 4; ++ot)
      smem[a * 1088 + (lg4 * 4 + r) * 68 + ot * 16 + l15] = scale * up[ot];
  }
  __syncthreads();

  // ---- phase 2: u A-frags (transpose read, split hi/lo)
  bf16x8 uah[2], ual[2];
#pragma unroll
  for (int kc = 0; kc < 2; ++kc) {
    float4 f0 = *(const float4*)&smem[a * 1088 + l15 * 68 + kc * 32 + k8];
    float4 f1 = *(const float4*)&smem[a * 1088 + l15 * 68 + kc * 32 + k8 + 4];
    float vv[8] = {f0.x, f0.y, f0.z, f0.w, f1.x, f1.y, f1.z, f1.w};
    BF8 vh, vl;
#pragma unroll
    for (int j = 0; j < 8; ++j) {
      unsigned short hi = f2bf(vv[j]);
      vh.u[j] = hi;
      vl.u[j] = f2bf(vv[j] - bf2f(hi));
    }
    uah[kc] = vh.b;
    ual[kc] = vl.b;
  }
  __syncthreads();  // u_scr dead; uc overlays it

  // ---- phase 3: u_hat MFMA (3-term split), f32 accum in registers
  f32x4 au[20];
#pragma unroll
  for (int nt = 0; nt < 20; ++nt) au[nt] = fz;
#pragma unroll
  for (int nt = 0; nt < 20; ++nt)
#pragma unroll
    for (int kc = 0; kc < 2; ++kc) {
      bf16x8 bh = *(const bf16x8*)(Wbh + ((size_t)(a * 320 + nt * 16 + l15) * 64 + kc * 32 + k8));
      bf16x8 bl = *(const bf16x8*)(Wbl + ((size_t)(a * 320 + nt * 16 + l15) * 64 + kc * 32 + k8));
      au[nt] = __builtin_amdgcn_mfma_f32_16x16x32_bf16(uah[kc], bh, au[nt], 0, 0, 0);
      au[nt] = __builtin_amdgcn_mfma_f32_16x16x32_bf16(ual[kc], bh, au[nt], 0, 0, 0);
      au[nt] = __builtin_amdgcn_mfma_f32_16x16x32_bf16(uah[kc], bl, au[nt], 0, 0, 0);
    }

  // ---- phase 4: streaming Gram accumulation (half 1 first, half 0 last so
  //      uc ends holding half 0 for the v pass)
  const int sid   = tid >> 4;
  const int jraw  = tid & 15;
  const bool jact = (jraw < 10);
  const int jj    = jact ? jraw : 9;
  const int rbase = sid * 204 + jj * 20;  // + ag*16*204

  float Gp[10];
#pragma unroll
  for (int p = 0; p < 10; ++p) Gp[p] = 0.f;

#pragma unroll
  for (int hh2 = 0; hh2 < 2; ++hh2) {
    const int half = 1 - hh2;
    if (hh2 > 0) __syncthreads();  // prev half's reads done before overwrite
#pragma unroll
    for (int q = 0; q < 10; ++q)
#pragma unroll
      for (int r = 0; r < 4; ++r)
        smem[(a * 16 + lg4 * 4 + r) * 204 + q * 20 + l15] = au[q * 2 + half][r];
    __syncthreads();
#pragma unroll
    for (int qq = 0; qq < 4; ++qq) {
      f32x4 f0 = *(const f32x4*)&smem[rbase + 0 * 3264 + qq * 4];
      f32x4 f1 = *(const f32x4*)&smem[rbase + 1 * 3264 + qq * 4];
      f32x4 f2 = *(const f32x4*)&smem[rbase + 2 * 3264 + qq * 4];
      f32x4 f3 = *(const f32x4*)&smem[rbase + 3 * 3264 + qq * 4];
#pragma unroll
      for (int e = 0; e < 4; ++e) {
        float v0 = f0[e], v1 = f1[e], v2 = f2[e], v3 = f3[e];
        Gp[0] += v0 * v0; Gp[1] += v0 * v1; Gp[2] += v0 * v2; Gp[3] += v0 * v3;
        Gp[4] += v1 * v1; Gp[5] += v1 * v2; Gp[6] += v1 * v3;
        Gp[7] += v2 * v2; Gp[8] += v2 * v3;
        Gp[9] += v3 * v3;
      }
    }
  }

  // ---- phase 5: 3 routing iterations on G (register-local)
  float cf0 = 0.f, cf1 = 0.f, cf2 = 0.f, cf3 = 0.f;
  {
    float lg0 = 0.f, lg1 = 0.f, lg2 = 0.f, lg3 = 0.f;
#pragma unroll
    for (int it = 0; it < 3; ++it) {
      float e0 = jact ? __expf(lg0) : 0.f;
      float e1 = jact ? __expf(lg1) : 0.f;
      float e2 = jact ? __expf(lg2) : 0.f;
      float e3 = jact ? __expf(lg3) : 0.f;
      float S0 = e0, S1 = e1, S2 = e2, S3 = e3;
#pragma unroll
      for (int m = 1; m <= 8; m <<= 1) {
        S0 += __shfl_xor(S0, m, 16);
        S1 += __shfl_xor(S1, m, 16);
        S2 += __shfl_xor(S2, m, 16);
        S3 += __shfl_xor(S3, m, 16);
      }
      float c0 = e0 / S0, c1 = e1 / S1, c2 = e2 / S2, c3 = e3 / S3;
      float t0 = c0 * Gp[0] + c1 * Gp[1] + c2 * Gp[2] + c3 * Gp[3];
      float t1 = c0 * Gp[1] + c1 * Gp[4] + c2 * Gp[5] + c3 * Gp[6];
      float t2 = c0 * Gp[2] + c1 * Gp[5] + c2 * Gp[7] + c3 * Gp[8];
      float t3 = c0 * Gp[3] + c1 * Gp[6] + c2 * Gp[8] + c3 * Gp[9];
      float sq = c0 * t0 + c1 * t1 + c2 * t2 + c3 * t3;
      float scale = sq / ((1.f + sq) * sqrtf(sq + 1e-8f));
      if (it < 2) {
        lg0 += scale * t0;
        lg1 += scale * t1;
        lg2 += scale * t2;
        lg3 += scale * t3;
      } else {
        cf0 = scale * c0;
        cf1 = scale * c1;
        cf2 = scale * c2;
        cf3 = scale * c3;
      }
    }
  }

  // ---- phase 6: v pass, streaming. uc holds half 0 (reads-after-reads ok).
  float* po = out + (size_t)(b0 + sid) * 320 + jraw * 32;
  if (jact) {
#pragma unroll
    for (int qq = 0; qq < 4; ++qq) {
      f32x4 f0 = *(const f32x4*)&smem[rbase + 0 * 3264 + qq * 4];
      f32x4 f1 = *(const f32x4*)&smem[rbase + 1 * 3264 + qq * 4];
      f32x4 f2 = *(const f32x4*)&smem[rbase + 2 * 3264 + qq * 4];
      f32x4 f3 = *(const f32x4*)&smem[rbase + 3 * 3264 + qq * 4];
      float st[4];
#pragma unroll
      for (int e = 0; e < 4; ++e)
        st[e] = cf0 * f0[e] + cf1 * f1[e] + cf2 * f2[e] + cf3 * f3[e];
      float4 v4 = {st[0], st[1], st[2], st[3]};
      *(float4*)(po + qq * 4) = v4;
    }
  }
  __syncthreads();  // v reads of half 0 done before overwrite
#pragma unroll
  for (int q = 0; q < 10; ++q)
#pragma unroll
    for (int r = 0; r < 4; ++r)
      smem[(a * 16 + lg4 * 4 + r) * 204 + q * 20 + l15] = au[q * 2 + 1][r];
  __syncthreads();
  if (jact) {
#pragma unroll
    for (int qq = 0; qq < 4; ++qq) {
      f32x4 f0 = *(const f32x4*)&smem[rbase + 0 * 3264 + qq * 4];
      f32x4 f1 = *(const f32x4*)&smem[rbase + 1 * 3264 + qq * 4];
      f32x4 f2 = *(const f32x4*)&smem[rbase + 2 * 3264 + qq * 4];
      f32x4 f3 = *(const f32x4*)&smem[rbase + 3 * 3264 + qq * 4];
      float st[4];
#pragma unroll
      for (int e = 0; e < 4; ++e)
        st[e] = cf0 * f0[e] + cf1 * f1[e] + cf2 * f2[e] + cf3 * f3[e];
      float4 v4 = {st[0], st[1], st[2], st[3]};
      *(float4*)(po + 16 + qq * 4) = v4;
    }
  }
}

extern "C" void kernel_launch(void* const* d_in, const int* in_sizes, int n_in,
                              void* d_out, int out_size, void* d_ws, size_t ws_size,
                              hipStream_t stream) {
  const float* x  = (const float*)d_in[0];
  const float* W1 = (const float*)d_in[1];
  const float* b1 = (const float*)d_in[2];
  const float* W2 = (const float*)d_in[3];
  const float* b2 = (const float*)d_in[4];
  const float* W  = (const float*)d_in[5];

  unsigned short* wsb = (unsigned short*)d_ws;
  unsigned short* W1h = wsb;                 // 204800
  unsigned short* W1l = wsb + 204800;        // 204800
  unsigned short* W2h = wsb + 409600;        // 16384
  unsigned short* W2l = wsb + 425984;        // 16384
  unsigned short* Wbh = wsb + 442368;        // 81920
  unsigned short* Wbl = wsb + 524288;        // 81920
  unsigned int*   H   = (unsigned int*)(wsb + 606208);  // 32768*256 u32
  float* out = (float*)d_out;

  kprep<<<800, 256, 0, stream>>>(W1, W2, W, W1h, W1l, W2h, W2l, Wbh, Wbl);
  kA<<<256, 256, 0, stream>>>(x, b1, W1h, W1l, H);
  kB<<<2048, 256, 0, stream>>>(H, b2, W2h, W2l, Wbh, Wbl, out);
}